// Round 1
// baseline (370.182 us; speedup 1.0000x reference)
//
#include <hip/hip_runtime.h>
#include <math.h>

#define DIM 256
#define QUEUE_N 48000
#define NCLS 126
#define BSZ 512
#define KNN 5
#define INV_TAU 14.285714285714286f
#define COEFF_V 0.1f
#define WARM 4000

// ---------------- K0: inverse norms --------------------------------------
// rows [0,512): tgt rows (features[512+r]);  rows [512, 512+48000): new_queue
// row q (features[q] if q<512 else queue[q]).  One wave per row.
__global__ __launch_bounds__(256) void k_norms(const float* __restrict__ feat,
                                               const float* __restrict__ queue,
                                               float* __restrict__ tinv,
                                               float* __restrict__ qinv) {
    int row  = blockIdx.x * 4 + (threadIdx.x >> 6);
    int lane = threadIdx.x & 63;
    const int TOT = BSZ + QUEUE_N;
    if (row >= TOT) return;
    const float* src;
    if (row < BSZ) {
        src = feat + (size_t)(BSZ + row) * DIM;
    } else {
        int q = row - BSZ;
        src = (q < BSZ) ? feat + (size_t)q * DIM : queue + (size_t)q * DIM;
    }
    float4 v = ((const float4*)src)[lane];
    float ss = v.x * v.x + v.y * v.y + v.z * v.z + v.w * v.w;
#pragma unroll
    for (int off = 32; off; off >>= 1) ss += __shfl_down(ss, off);
    if (lane == 0) {
        float inv = 1.0f / fmaxf(sqrtf(ss), 1e-12f);
        if (row < BSZ) tinv[row] = inv;
        else           qinv[row - BSZ] = inv;
    }
}

// ---------------- K1: fp32 GEMM  sim = Tn * Qn^T -------------------------
// A = tgt raw (512x256), B = new_queue raw (48000x256), both row-major (NT).
// Epilogue scales by tinv[m]*qinv[n].  BM=BN=64, BK=32, 4x4 micro-tile.
#define BM 64
#define BN 64
#define BK 32

__global__ __launch_bounds__(256) void k_gemm(const float* __restrict__ feat,
                                              const float* __restrict__ queue,
                                              const float* __restrict__ tinv,
                                              const float* __restrict__ qinv,
                                              float* __restrict__ sim) {
    __shared__ float As[BK][BM + 4];
    __shared__ float Bs[BK][BN + 4];
    const int bm = blockIdx.x;      // 0..7
    const int bn = blockIdx.y;      // 0..749
    const int t  = threadIdx.x;
    const int tx = t & 15;          // col group
    const int ty = t >> 4;          // row group
    const int m0 = bm * BM, n0 = bn * BN;
    const float* A = feat + (size_t)BSZ * DIM;   // tgt rows

    const int lr = t >> 3;          // 0..31  (tile row for loads)
    const int lc = (t & 7) * 4;     // 0..28  (k offset for loads)

    float acc[4][4] = {};

    for (int k0 = 0; k0 < DIM; k0 += BK) {
        float4 a0 = *(const float4*)(A + (size_t)(m0 + lr) * DIM + k0 + lc);
        float4 a1 = *(const float4*)(A + (size_t)(m0 + lr + 32) * DIM + k0 + lc);
        int qr0 = n0 + lr, qr1 = n0 + lr + 32;
        const float* b0p = (qr0 < BSZ) ? feat + (size_t)qr0 * DIM : queue + (size_t)qr0 * DIM;
        const float* b1p = (qr1 < BSZ) ? feat + (size_t)qr1 * DIM : queue + (size_t)qr1 * DIM;
        float4 b0 = *(const float4*)(b0p + k0 + lc);
        float4 b1 = *(const float4*)(b1p + k0 + lc);

        __syncthreads();
        As[lc + 0][lr] = a0.x; As[lc + 1][lr] = a0.y; As[lc + 2][lr] = a0.z; As[lc + 3][lr] = a0.w;
        As[lc + 0][lr + 32] = a1.x; As[lc + 1][lr + 32] = a1.y; As[lc + 2][lr + 32] = a1.z; As[lc + 3][lr + 32] = a1.w;
        Bs[lc + 0][lr] = b0.x; Bs[lc + 1][lr] = b0.y; Bs[lc + 2][lr] = b0.z; Bs[lc + 3][lr] = b0.w;
        Bs[lc + 0][lr + 32] = b1.x; Bs[lc + 1][lr + 32] = b1.y; Bs[lc + 2][lr + 32] = b1.z; Bs[lc + 3][lr + 32] = b1.w;
        __syncthreads();

#pragma unroll
        for (int k = 0; k < BK; ++k) {
            float4 av = *(const float4*)&As[k][ty * 4];
            float4 bv = *(const float4*)&Bs[k][tx * 4];
            float a_[4] = {av.x, av.y, av.z, av.w};
            float b_[4] = {bv.x, bv.y, bv.z, bv.w};
#pragma unroll
            for (int i = 0; i < 4; ++i)
#pragma unroll
                for (int j = 0; j < 4; ++j)
                    acc[i][j] = fmaf(a_[i], b_[j], acc[i][j]);
        }
    }

    const int m_ = m0 + ty * 4;
    const int n_ = n0 + tx * 4;
    float ti4[4], qi4[4];
#pragma unroll
    for (int i = 0; i < 4; ++i) ti4[i] = tinv[m_ + i];
#pragma unroll
    for (int j = 0; j < 4; ++j) qi4[j] = qinv[n_ + j];
#pragma unroll
    for (int i = 0; i < 4; ++i) {
        float4 o;
        o.x = acc[i][0] * ti4[i] * qi4[0];
        o.y = acc[i][1] * ti4[i] * qi4[1];
        o.z = acc[i][2] * ti4[i] * qi4[2];
        o.w = acc[i][3] * ti4[i] * qi4[3];
        *(float4*)&sim[(size_t)(m_ + i) * QUEUE_N + n_] = o;
    }
}

// ---------------- K2: per-row stats --------------------------------------
// Per target row: sumexp (shifted by C=1/tau), per-class sim sums, top-5.
__global__ __launch_bounds__(256) void k_rowstats(const float* __restrict__ sim,
                                                  const int* __restrict__ slab,
                                                  const int* __restrict__ qlab,
                                                  float* __restrict__ S,
                                                  float* __restrict__ sumexp,
                                                  float* __restrict__ t5v,
                                                  int* __restrict__ t5i) {
    const int row = blockIdx.x;
    const float* sr = sim + (size_t)row * QUEUE_N;
    __shared__ float bins[NCLS];
    __shared__ float mv[4 * KNN];
    __shared__ int   mi[4 * KNN];
    __shared__ float wsum[4];
    const int t = threadIdx.x;
    if (t < NCLS) bins[t] = 0.0f;
    __syncthreads();

    float se = 0.0f;
    float v[KNN];
    int   id[KNN];
#pragma unroll
    for (int q = 0; q < KNN; ++q) { v[q] = -3.402823466e38f; id[q] = 0x7fffffff; }

    for (int j4 = t; j4 < QUEUE_N / 4; j4 += 256) {
        float4 s4 = ((const float4*)sr)[j4];
        int j = j4 * 4;
        float sv[4] = {s4.x, s4.y, s4.z, s4.w};
#pragma unroll
        for (int e = 0; e < 4; ++e) {
            float s = sv[e];
            int jj = j + e;
            se += __expf((s - 1.0f) * INV_TAU);
            int lb = (jj < BSZ) ? slab[jj] : qlab[jj];
            atomicAdd(&bins[lb], s);
            if (s > v[KNN - 1] || (s == v[KNN - 1] && jj < id[KNN - 1])) {
                v[KNN - 1] = s; id[KNN - 1] = jj;
#pragma unroll
                for (int q = KNN - 1; q > 0; --q) {
                    bool sw = (v[q] > v[q - 1]) || (v[q] == v[q - 1] && id[q] < id[q - 1]);
                    if (sw) {
                        float tv = v[q]; v[q] = v[q - 1]; v[q - 1] = tv;
                        int ti_ = id[q]; id[q] = id[q - 1]; id[q - 1] = ti_;
                    }
                }
            }
        }
    }

    // wave-level merge (sorted desc lists) + sum reduce
#pragma unroll
    for (int off = 32; off; off >>= 1) {
        float ov[KNN]; int oi[KNN];
#pragma unroll
        for (int q = 0; q < KNN; ++q) { ov[q] = __shfl_down(v[q], off); oi[q] = __shfl_down(id[q], off); }
        float rv[KNN]; int ri[KNN];
        int a = 0, b = 0;
#pragma unroll
        for (int q = 0; q < KNN; ++q) {
            bool ta = (v[a] > ov[b]) || (v[a] == ov[b] && id[a] < oi[b]);
            if (ta) { rv[q] = v[a]; ri[q] = id[a]; ++a; }
            else    { rv[q] = ov[b]; ri[q] = oi[b]; ++b; }
        }
#pragma unroll
        for (int q = 0; q < KNN; ++q) { v[q] = rv[q]; id[q] = ri[q]; }
        se += __shfl_down(se, off);
    }
    if ((t & 63) == 0) {
        int w = t >> 6;
        wsum[w] = se;
#pragma unroll
        for (int q = 0; q < KNN; ++q) { mv[w * KNN + q] = v[q]; mi[w * KNN + q] = id[q]; }
    }
    __syncthreads();
    if (t < NCLS) S[(size_t)row * NCLS + t] = bins[t];
    if (t == 0) {
        int p[4] = {0, 0, 0, 0};
        for (int q = 0; q < KNN; ++q) {
            int bw = -1; float bv2 = 0.0f; int bi2 = 0;
            for (int w = 0; w < 4; ++w) {
                if (p[w] < KNN) {
                    float cv = mv[w * KNN + p[w]];
                    int   ci = mi[w * KNN + p[w]];
                    if (bw < 0 || cv > bv2 || (cv == bv2 && ci < bi2)) { bw = w; bv2 = cv; bi2 = ci; }
                }
            }
            t5v[(size_t)row * KNN + q] = bv2;
            t5i[(size_t)row * KNN + q] = bi2;
            p[bw]++;
        }
        sumexp[row] = wsum[0] + wsum[1] + wsum[2] + wsum[3];
    }
}

// ---------------- K3: votes, pseudo, loss --------------------------------
__global__ __launch_bounds__(256) void k_final(const int* __restrict__ slab,
                                               const int* __restrict__ qlab,
                                               const int* __restrict__ itp,
                                               const float* __restrict__ S,
                                               const float* __restrict__ sumexp,
                                               const int* __restrict__ t5i,
                                               float* __restrict__ out) {
    __shared__ int cnt[NCLS];
    __shared__ float red[256];
    const int t = threadIdx.x;
    if (t < NCLS) cnt[t] = 0;
    __syncthreads();
    for (int j = t; j < QUEUE_N; j += 256) {
        int lb = (j < BSZ) ? slab[j] : qlab[j];
        atomicAdd(&cnt[lb], 1);
    }
    __syncthreads();
    float local = 0.0f;
    for (int r = t; r < BSZ; r += 256) {
        int lab[KNN];
#pragma unroll
        for (int q = 0; q < KNN; ++q) {
            int j = t5i[(size_t)r * KNN + q];
            lab[q] = (j < BSZ) ? slab[j] : qlab[j];
        }
        // argmax over one-hot vote counts; ties -> smallest class index
        int bestc = 0, bestl = 0x7fffffff;
#pragma unroll
        for (int q = 0; q < KNN; ++q) {
            int c = 0;
#pragma unroll
            for (int w = 0; w < KNN; ++w) c += (lab[w] == lab[q]) ? 1 : 0;
            if (c > bestc || (c == bestc && lab[q] < bestl)) { bestc = c; bestl = lab[q]; }
        }
        int pc = cnt[bestl];
        float lse = logf(sumexp[r]) + INV_TAU;
        float sc = S[(size_t)r * NCLS + bestl];
        float denom = fmaxf((float)pc, 1.0f);
        float per = -(sc * INV_TAU - (float)pc * lse) / denom;
        local += per;
    }
    red[t] = local;
    __syncthreads();
    for (int s2 = 128; s2; s2 >>= 1) {
        if (t < s2) red[t] += red[t + s2];
        __syncthreads();
    }
    if (t == 0) {
        float coeff = (itp[0] > WARM) ? COEFF_V : 0.0f;
        out[0] = coeff * (red[0] / (float)BSZ);
    }
}

// ---------------- launcher ----------------------------------------------
extern "C" void kernel_launch(void* const* d_in, const int* in_sizes, int n_in,
                              void* d_out, int out_size, void* d_ws, size_t ws_size,
                              hipStream_t stream) {
    const float* feat  = (const float*)d_in[0];
    const int*   slab  = (const int*)d_in[1];
    const int*   itp   = (const int*)d_in[2];
    const float* queue = (const float*)d_in[3];
    const int*   qlab  = (const int*)d_in[4];
    float* out = (float*)d_out;

    char* ws = (char*)d_ws;
    float* sim    = (float*)ws;                            // 512*48000 f32 = 98,304,000 B
    float* tinv   = (float*)(ws + 98304000);               // 512
    float* qinv   = tinv + BSZ;                            // 48000
    float* sumexp = qinv + QUEUE_N;                        // 512
    float* S      = sumexp + BSZ;                          // 512*126
    float* t5v    = S + BSZ * NCLS;                        // 512*5
    int*   t5i    = (int*)(t5v + BSZ * KNN);               // 512*5

    hipLaunchKernelGGL(k_norms, dim3((BSZ + QUEUE_N + 3) / 4), dim3(256), 0, stream,
                       feat, queue, tinv, qinv);
    hipLaunchKernelGGL(k_gemm, dim3(BSZ / BM, QUEUE_N / BN), dim3(256), 0, stream,
                       feat, queue, tinv, qinv, sim);
    hipLaunchKernelGGL(k_rowstats, dim3(BSZ), dim3(256), 0, stream,
                       sim, slab, qlab, S, sumexp, t5v, t5i);
    hipLaunchKernelGGL(k_final, dim3(1), dim3(256), 0, stream,
                       slab, qlab, itp, S, sumexp, t5i, out);
}

// Round 2
// 328.130 us; speedup vs baseline: 1.1282x; 1.1282x over previous
//
#include <hip/hip_runtime.h>
#include <math.h>

#define DIM 256
#define NQ 48000
#define NCLS 126
#define BSZ 512
#define KNN 5
#define INV_TAU 14.285714285714286f
#define COEFF_V 0.1f
#define WARM 4000

#define BM 128
#define BN 128
#define BK 64
#define NCHUNK (NQ / BN)   /* 375 */

typedef __attribute__((ext_vector_type(8))) short bf16x8;
typedef __attribute__((ext_vector_type(4))) float f32x4;

__device__ __forceinline__ unsigned short f2bf(float f) {
    unsigned u = __float_as_uint(f);
    u += 0x7fffu + ((u >> 16) & 1u);
    return (unsigned short)(u >> 16);
}
__device__ __forceinline__ float bf2f(unsigned short h) {
    return __uint_as_float(((unsigned)h) << 16);
}

// merge two sorted-desc top-5 lists (ties: smaller index wins); a+b==q<5 so no OOB
__device__ __forceinline__ void merge5(float* v, int* id, const float* ov, const int* oi) {
    float rv[KNN]; int ri[KNN];
    int a = 0, b = 0;
#pragma unroll
    for (int q = 0; q < KNN; ++q) {
        bool ta = (v[a] > ov[b]) || (v[a] == ov[b] && id[a] < oi[b]);
        if (ta) { rv[q] = v[a]; ri[q] = id[a]; ++a; }
        else    { rv[q] = ov[b]; ri[q] = oi[b]; ++b; }
    }
#pragma unroll
    for (int q = 0; q < KNN; ++q) { v[q] = rv[q]; id[q] = ri[q]; }
}

// ---------- K0: normalize + bf16 pack.  rows [0,512): Tn (=tgt), [512,512+48000): Qn ----
__global__ __launch_bounds__(256) void k_prep(const float* __restrict__ feat,
                                              const float* __restrict__ queue,
                                              unsigned short* __restrict__ Tn,
                                              unsigned short* __restrict__ Qn) {
    int row  = blockIdx.x * 4 + (threadIdx.x >> 6);
    int lane = threadIdx.x & 63;
    if (row >= BSZ + NQ) return;
    const float* src;
    unsigned short* dst;
    if (row < BSZ) { src = feat + (size_t)(BSZ + row) * DIM; dst = Tn + (size_t)row * DIM; }
    else {
        int q = row - BSZ;
        src = (q < BSZ) ? feat + (size_t)q * DIM : queue + (size_t)q * DIM;
        dst = Qn + (size_t)q * DIM;
    }
    float4 v = ((const float4*)src)[lane];
    float ss = v.x * v.x + v.y * v.y + v.z * v.z + v.w * v.w;
#pragma unroll
    for (int off = 32; off; off >>= 1) ss += __shfl_xor(ss, off);
    float inv = 1.0f / fmaxf(sqrtf(ss), 1e-12f);
    ushort4 o = make_ushort4(f2bf(v.x * inv), f2bf(v.y * inv), f2bf(v.z * inv), f2bf(v.w * inv));
    *(ushort4*)(dst + lane * 4) = o;
}

// ---------- K1: per-block partial class sums + label counts ---------------------------
__global__ __launch_bounds__(1024) void k_cs(const unsigned short* __restrict__ Qn,
                                             const int* __restrict__ slab,
                                             const int* __restrict__ qlab,
                                             float* __restrict__ pcs,   // [128][126][256]
                                             int* __restrict__ pcnt) {  // [128][126]
    __shared__ float bins[NCLS][128];
    __shared__ int ibins[NCLS];
    const int b = blockIdx.x;
    const int t = threadIdx.x;
    const int rp = t >> 7;       // 0..7 row-parallel group
    const int col = t & 127;
    const int r0 = b * (NQ / 128);   // 375 rows per block
    for (int half = 0; half < 2; ++half) {
        for (int i = t; i < NCLS * 128; i += 1024) ((float*)bins)[i] = 0.0f;
        if (half == 0) for (int i = t; i < NCLS; i += 1024) ibins[i] = 0;
        __syncthreads();
        for (int i = rp; i < NQ / 128; i += 8) {
            int row = r0 + i;
            int lb = (row < BSZ) ? slab[row] : qlab[row];
            float val = bf2f(Qn[(size_t)row * DIM + half * 128 + col]);
            atomicAdd(&bins[lb][col], val);
            if (half == 0 && col == 0) atomicAdd(&ibins[lb], 1);
        }
        __syncthreads();
        for (int c = rp; c < NCLS; c += 8)
            pcs[((size_t)b * NCLS + c) * DIM + half * 128 + col] = bins[c][col];
        if (half == 0) for (int i = t; i < NCLS; i += 1024) pcnt[b * NCLS + i] = ibins[i];
        __syncthreads();
    }
}

// ---------- K2: reduce partials -> CS[126][256], cnt[126] -----------------------------
__global__ __launch_bounds__(256) void k_cs_reduce(const float* __restrict__ pcs,
                                                   const int* __restrict__ pcnt,
                                                   float* __restrict__ CS,
                                                   int* __restrict__ cnt) {
    int c = blockIdx.x, d = threadIdx.x;
    float s = 0.0f;
    for (int b = 0; b < 128; ++b) s += pcs[((size_t)b * NCLS + c) * DIM + d];
    CS[(size_t)c * DIM + d] = s;
    if (d == 0) {
        int ic = 0;
        for (int b = 0; b < 128; ++b) ic += pcnt[b * NCLS + c];
        cnt[c] = ic;
    }
}

// ---------- K3: bf16 MFMA GEMM tile + fused per-row partial stats ---------------------
// grid (375, 4); 4 waves in 2x2; each wave 64x64 via 16x16x32 MFMA.
union SMemU { short bs[BN][72]; float sim[64][132]; };

__global__ __launch_bounds__(256) void k_gemm_fused(const unsigned short* __restrict__ Tn,
                                                    const unsigned short* __restrict__ Qn,
                                                    float* __restrict__ pse,   // [375][512]
                                                    float* __restrict__ pv5,   // [375][512][5]
                                                    int*   __restrict__ pi5) {
    __shared__ SMemU sm;
    const int bn = blockIdx.x, bm = blockIdx.y;
    const int t = threadIdx.x;
    const int wid = t >> 6, lane = t & 63;
    const int wr = wid >> 1, wc = wid & 1;
    const int c16 = lane & 15, g = lane >> 4;
    const int m0 = bm * BM, n0 = bn * BN;

    f32x4 acc[4][4];
#pragma unroll
    for (int m = 0; m < 4; ++m)
#pragma unroll
        for (int n = 0; n < 4; ++n) acc[m][n] = (f32x4){0.f, 0.f, 0.f, 0.f};

    const int sr = t >> 3;   // 0..31
    const int sg = t & 7;    // 16B segment

    for (int k0 = 0; k0 < DIM; k0 += BK) {
        __syncthreads();
#pragma unroll
        for (int i = 0; i < 4; ++i) {
            int r = sr + i * 32;
            *(uint4*)&sm.bs[r][sg * 8] =
                *(const uint4*)(Qn + (size_t)(n0 + r) * DIM + k0 + sg * 8);
        }
        __syncthreads();
#pragma unroll
        for (int kk = 0; kk < 2; ++kk) {
            bf16x8 aF[4], bF[4];
#pragma unroll
            for (int m = 0; m < 4; ++m)
                aF[m] = *(const bf16x8*)(Tn + (size_t)(m0 + wr * 64 + m * 16 + c16) * DIM
                                         + k0 + kk * 32 + g * 8);
#pragma unroll
            for (int n = 0; n < 4; ++n)
                bF[n] = *(const bf16x8*)&sm.bs[wc * 64 + n * 16 + c16][kk * 32 + g * 8];
#pragma unroll
            for (int m = 0; m < 4; ++m)
#pragma unroll
                for (int n = 0; n < 4; ++n)
                    acc[m][n] = __builtin_amdgcn_mfma_f32_16x16x32_bf16(aF[m], bF[n], acc[m][n], 0, 0, 0);
        }
    }

    // fused epilogue: two 64-row phases through LDS
    for (int ph = 0; ph < 2; ++ph) {
        __syncthreads();
        if (wr == ph) {
#pragma unroll
            for (int m = 0; m < 4; ++m)
#pragma unroll
                for (int n = 0; n < 4; ++n)
#pragma unroll
                    for (int j = 0; j < 4; ++j)
                        sm.sim[m * 16 + g * 4 + j][wc * 64 + n * 16 + c16] = acc[m][n][j];
        }
        __syncthreads();
        const int lrow = t >> 2, h = t & 3;
        float v[KNN]; int id[KNN];
#pragma unroll
        for (int q = 0; q < KNN; ++q) { v[q] = -3.402823466e38f; id[q] = 0x7fffffff; }
        float se = 0.0f;
#pragma unroll
        for (int i = 0; i < 8; ++i) {
            float4 s4 = *(const float4*)&sm.sim[lrow][h * 32 + i * 4];
            float sv4[4] = {s4.x, s4.y, s4.z, s4.w};
#pragma unroll
            for (int e = 0; e < 4; ++e) {
                float s = sv4[e];
                int cg = n0 + h * 32 + i * 4 + e;
                se += __expf((s - 1.0f) * INV_TAU);
                if (s > v[KNN - 1] || (s == v[KNN - 1] && cg < id[KNN - 1])) {
                    v[KNN - 1] = s; id[KNN - 1] = cg;
#pragma unroll
                    for (int q = KNN - 1; q > 0; --q) {
                        bool sw = (v[q] > v[q - 1]) || (v[q] == v[q - 1] && id[q] < id[q - 1]);
                        if (sw) {
                            float tv = v[q]; v[q] = v[q - 1]; v[q - 1] = tv;
                            int ti = id[q]; id[q] = id[q - 1]; id[q - 1] = ti;
                        }
                    }
                }
            }
        }
        // merge the 4 h-threads of this row (lanes t^1, t^2 in-wave)
#pragma unroll
        for (int off = 1; off <= 2; off <<= 1) {
            float ov[KNN]; int oi[KNN];
#pragma unroll
            for (int q = 0; q < KNN; ++q) { ov[q] = __shfl_xor(v[q], off); oi[q] = __shfl_xor(id[q], off); }
            float ose = __shfl_xor(se, off);
            merge5(v, id, ov, oi);
            se += ose;
        }
        if (h == 0) {
            int grow = m0 + ph * 64 + lrow;
            pse[(size_t)bn * BSZ + grow] = se;
#pragma unroll
            for (int q = 0; q < KNN; ++q) {
                pv5[((size_t)bn * BSZ + grow) * KNN + q] = v[q];
                pi5[((size_t)bn * BSZ + grow) * KNN + q] = id[q];
            }
        }
    }
}

// ---------- K4: merge 375 chunk partials per row -> lse, pseudo -----------------------
__global__ __launch_bounds__(128) void k_merge(const float* __restrict__ pse,
                                               const float* __restrict__ pv5,
                                               const int* __restrict__ pi5,
                                               const int* __restrict__ slab,
                                               const int* __restrict__ qlab,
                                               float* __restrict__ lse,
                                               int* __restrict__ pseudo) {
    const int row = blockIdx.x, t = threadIdx.x;
    float v[KNN]; int id[KNN];
#pragma unroll
    for (int q = 0; q < KNN; ++q) { v[q] = -3.402823466e38f; id[q] = 0x7fffffff; }
    float se = 0.0f;
    for (int c = t; c < NCHUNK; c += 128) {
        se += pse[(size_t)c * BSZ + row];
        float lv[KNN]; int li[KNN];
#pragma unroll
        for (int q = 0; q < KNN; ++q) {
            lv[q] = pv5[((size_t)c * BSZ + row) * KNN + q];
            li[q] = pi5[((size_t)c * BSZ + row) * KNN + q];
        }
        merge5(v, id, lv, li);
    }
#pragma unroll
    for (int off = 32; off; off >>= 1) {
        float ov[KNN]; int oi[KNN];
#pragma unroll
        for (int q = 0; q < KNN; ++q) { ov[q] = __shfl_down(v[q], off); oi[q] = __shfl_down(id[q], off); }
        float ose = __shfl_down(se, off);
        merge5(v, id, ov, oi);
        se += ose;
    }
    __shared__ float sv[2][KNN]; __shared__ int si[2][KNN]; __shared__ float ssum[2];
    if ((t & 63) == 0) {
        int w = t >> 6;
        ssum[w] = se;
#pragma unroll
        for (int q = 0; q < KNN; ++q) { sv[w][q] = v[q]; si[w][q] = id[q]; }
    }
    __syncthreads();
    if (t == 0) {
        float av[KNN]; int ai[KNN];
#pragma unroll
        for (int q = 0; q < KNN; ++q) { av[q] = sv[0][q]; ai[q] = si[0][q]; }
        merge5(av, ai, sv[1], si[1]);
        float tot = ssum[0] + ssum[1];
        int lab[KNN];
#pragma unroll
        for (int q = 0; q < KNN; ++q) {
            int j = ai[q];
            lab[q] = (j < BSZ) ? slab[j] : qlab[j];
        }
        int bestc = 0, bestl = 0x7fffffff;
#pragma unroll
        for (int q = 0; q < KNN; ++q) {
            int c2 = 0;
#pragma unroll
            for (int w = 0; w < KNN; ++w) c2 += (lab[w] == lab[q]) ? 1 : 0;
            if (c2 > bestc || (c2 == bestc && lab[q] < bestl)) { bestc = c2; bestl = lab[q]; }
        }
        pseudo[row] = bestl;
        lse[row] = logf(tot) + INV_TAU;
    }
}

// ---------- K5: per-row loss via S = Tn[row] . CS[pseudo] -----------------------------
__global__ __launch_bounds__(256) void k_loss(const unsigned short* __restrict__ Tn,
                                              const float* __restrict__ CS,
                                              const int* __restrict__ cnt,
                                              const float* __restrict__ lse,
                                              const int* __restrict__ pseudo,
                                              float* __restrict__ rowloss) {
    int row  = blockIdx.x * 4 + (threadIdx.x >> 6);
    int lane = threadIdx.x & 63;
    int ps = pseudo[row];
    ushort4 tv = *(const ushort4*)(Tn + (size_t)row * DIM + lane * 4);
    float4  cv = *(const float4*)(CS + (size_t)ps * DIM + lane * 4);
    float d = bf2f(tv.x) * cv.x + bf2f(tv.y) * cv.y + bf2f(tv.z) * cv.z + bf2f(tv.w) * cv.w;
#pragma unroll
    for (int off = 32; off; off >>= 1) d += __shfl_down(d, off);
    if (lane == 0) {
        float pc = (float)cnt[ps];
        rowloss[row] = -(d * INV_TAU - pc * lse[row]) / fmaxf(pc, 1.0f);
    }
}

// ---------- K6: final reduction --------------------------------------------------------
__global__ __launch_bounds__(256) void k_final(const float* __restrict__ rowloss,
                                               const int* __restrict__ itp,
                                               float* __restrict__ out) {
    __shared__ float red[256];
    int t = threadIdx.x;
    red[t] = rowloss[t] + rowloss[t + 256];
    __syncthreads();
    for (int k = 128; k; k >>= 1) {
        if (t < k) red[t] += red[t + k];
        __syncthreads();
    }
    if (t == 0) out[0] = ((itp[0] > WARM) ? COEFF_V : 0.0f) * (red[0] / (float)BSZ);
}

// ---------- launcher -------------------------------------------------------------------
extern "C" void kernel_launch(void* const* d_in, const int* in_sizes, int n_in,
                              void* d_out, int out_size, void* d_ws, size_t ws_size,
                              hipStream_t stream) {
    const float* feat  = (const float*)d_in[0];
    const int*   slab  = (const int*)d_in[1];
    const int*   itp   = (const int*)d_in[2];
    const float* queue = (const float*)d_in[3];
    const int*   qlab  = (const int*)d_in[4];
    float* out = (float*)d_out;

    char* ws = (char*)d_ws;
    unsigned short* Qn = (unsigned short*)(ws);                    // 24,576,000 B
    unsigned short* Tn = (unsigned short*)(ws + 24576000);         //    262,144 B
    float* CS      = (float*)(ws + 24838144);                      //    129,024 B
    float* pcs     = (float*)(ws + 24967168);                      // 16,515,072 B
    int*   pcnt    = (int*)  (ws + 41482240);                      //     64,512 B
    int*   cnt     = (int*)  (ws + 41546752);                      //        512 B
    float* pse     = (float*)(ws + 41547264);                      //    768,000 B
    float* pv5     = (float*)(ws + 42315264);                      //  3,840,000 B
    int*   pi5     = (int*)  (ws + 46155264);                      //  3,840,000 B
    float* lse     = (float*)(ws + 49995264);                      //      2,048 B
    int*   pseudo  = (int*)  (ws + 49997312);                      //      2,048 B
    float* rowloss = (float*)(ws + 49999360);                      //      2,048 B

    hipLaunchKernelGGL(k_prep, dim3((BSZ + NQ) / 4), dim3(256), 0, stream, feat, queue, Tn, Qn);
    hipLaunchKernelGGL(k_cs, dim3(128), dim3(1024), 0, stream, Qn, slab, qlab, pcs, pcnt);
    hipLaunchKernelGGL(k_cs_reduce, dim3(NCLS), dim3(256), 0, stream, pcs, pcnt, CS, cnt);
    hipLaunchKernelGGL(k_gemm_fused, dim3(NCHUNK, BSZ / BM), dim3(256), 0, stream, Tn, Qn, pse, pv5, pi5);
    hipLaunchKernelGGL(k_merge, dim3(BSZ), dim3(128), 0, stream, pse, pv5, pi5, slab, qlab, lse, pseudo);
    hipLaunchKernelGGL(k_loss, dim3(BSZ / 4), dim3(256), 0, stream, Tn, CS, cnt, lse, pseudo, rowloss);
    hipLaunchKernelGGL(k_final, dim3(1), dim3(256), 0, stream, rowloss, itp, out);
}

// Round 3
// 273.375 us; speedup vs baseline: 1.3541x; 1.2003x over previous
//
#include <hip/hip_runtime.h>
#include <math.h>

#define DIM 256
#define NQ 48000
#define NCLS 126
#define BSZ 512
#define KNN 5
#define INV_TAU 14.285714285714286f
#define COEFF_V 0.1f
#define WARM 4000

#define BM 128
#define BN 128
#define BK 64
#define NCHUNK (NQ / BN)   /* 375 */

typedef __attribute__((ext_vector_type(8))) short bf16x8;
typedef __attribute__((ext_vector_type(4))) float f32x4;

#define NEG_INF -3.402823466e38f

__device__ __forceinline__ unsigned short f2bf(float f) {
    unsigned u = __float_as_uint(f);
    u += 0x7fffu + ((u >> 16) & 1u);
    return (unsigned short)(u >> 16);
}
__device__ __forceinline__ float bf2f(unsigned short h) {
    return __uint_as_float(((unsigned)h) << 16);
}

// Branchless merge of two sorted-desc top-5 lists into (av,ai).
// Only compile-time indices: heads at [0], conditional shifts. ~100 VALU ops,
// fully register-resident (rule #20: no runtime-indexed arrays).
__device__ __forceinline__ void merge5(float (&av)[KNN], int (&ai)[KNN],
                                       float (&bv)[KNN], int (&bi)[KNN]) {
    float rv[KNN]; int ri[KNN];
#pragma unroll
    for (int q = 0; q < KNN; ++q) {
        bool ta = (av[0] > bv[0]) || (av[0] == bv[0] && ai[0] < bi[0]);
        rv[q] = ta ? av[0] : bv[0];
        ri[q] = ta ? ai[0] : bi[0];
        if (q < KNN - 1) {
#pragma unroll
            for (int i = 0; i < KNN - 1; ++i) {
                float sav = av[i + 1], sbv = bv[i + 1];
                int   sai = ai[i + 1], sbi = bi[i + 1];
                av[i] = ta ? sav : av[i];  ai[i] = ta ? sai : ai[i];
                bv[i] = ta ? bv[i] : sbv;  bi[i] = ta ? bi[i] : sbi;
            }
        }
    }
#pragma unroll
    for (int q = 0; q < KNN; ++q) { av[q] = rv[q]; ai[q] = ri[q]; }
}

// ---------- K0: normalize + bf16 pack ------------------------------------------------
__global__ __launch_bounds__(256) void k_prep(const float* __restrict__ feat,
                                              const float* __restrict__ queue,
                                              unsigned short* __restrict__ Tn,
                                              unsigned short* __restrict__ Qn) {
    int row  = blockIdx.x * 4 + (threadIdx.x >> 6);
    int lane = threadIdx.x & 63;
    if (row >= BSZ + NQ) return;
    const float* src;
    unsigned short* dst;
    if (row < BSZ) { src = feat + (size_t)(BSZ + row) * DIM; dst = Tn + (size_t)row * DIM; }
    else {
        int q = row - BSZ;
        src = (q < BSZ) ? feat + (size_t)q * DIM : queue + (size_t)q * DIM;
        dst = Qn + (size_t)q * DIM;
    }
    float4 v = ((const float4*)src)[lane];
    float ss = v.x * v.x + v.y * v.y + v.z * v.z + v.w * v.w;
#pragma unroll
    for (int off = 32; off; off >>= 1) ss += __shfl_xor(ss, off);
    float inv = 1.0f / fmaxf(sqrtf(ss), 1e-12f);
    ushort4 o = make_ushort4(f2bf(v.x * inv), f2bf(v.y * inv), f2bf(v.z * inv), f2bf(v.w * inv));
    *(ushort4*)(dst + lane * 4) = o;
}

// ---------- zero scratch -------------------------------------------------------------
__global__ __launch_bounds__(256) void k_zero(float* __restrict__ CS,
                                              int* __restrict__ cnt,
                                              int* __restrict__ cnt2) {
    int i = blockIdx.x * 256 + threadIdx.x;
    if (i < NCLS * DIM) CS[i] = 0.0f;
    if (i < NCLS) { cnt[i] = 0; cnt2[i] = 0; }
}

// ---------- label histogram ----------------------------------------------------------
__global__ __launch_bounds__(256) void k_hist(const int* __restrict__ slab,
                                              const int* __restrict__ qlab,
                                              int* __restrict__ cnt) {
    int r = blockIdx.x * 256 + threadIdx.x;
    if (r < NQ) {
        int lb = (r < BSZ) ? slab[r] : qlab[r];
        atomicAdd(&cnt[lb], 1);
    }
}

// ---------- exclusive prefix over 126 classes ----------------------------------------
__global__ void k_prefix(const int* __restrict__ cnt, int* __restrict__ off) {
    if (threadIdx.x == 0) {
        int acc = 0;
        for (int c = 0; c < NCLS; ++c) { off[c] = acc; acc += cnt[c]; }
        off[NCLS] = acc;
    }
}

// ---------- scatter row ids into per-class lists -------------------------------------
__global__ __launch_bounds__(256) void k_scatter(const int* __restrict__ slab,
                                                 const int* __restrict__ qlab,
                                                 const int* __restrict__ off,
                                                 int* __restrict__ cnt2,
                                                 int* __restrict__ list) {
    int r = blockIdx.x * 256 + threadIdx.x;
    if (r < NQ) {
        int lb = (r < BSZ) ? slab[r] : qlab[r];
        int idx = atomicAdd(&cnt2[lb], 1);
        list[off[lb] + idx] = r;
    }
}

// ---------- per-class feature sums: CS[c][d] = sum_{rows of c} Qn[row][d] ------------
__global__ __launch_bounds__(256) void k_cs2(const unsigned short* __restrict__ Qn,
                                             const int* __restrict__ off,
                                             const int* __restrict__ list,
                                             float* __restrict__ CS) {
    const int c = blockIdx.x;
    const int part = blockIdx.y;   // 0..7
    const int d = threadIdx.x;
    const int s1 = off[c + 1];
    float acc = 0.0f;
    int i = off[c] + part;
    for (; i + 24 < s1; i += 32) {
        int r0 = list[i], r1 = list[i + 8], r2 = list[i + 16], r3 = list[i + 24];
        float a0 = bf2f(Qn[(size_t)r0 * DIM + d]);
        float a1 = bf2f(Qn[(size_t)r1 * DIM + d]);
        float a2 = bf2f(Qn[(size_t)r2 * DIM + d]);
        float a3 = bf2f(Qn[(size_t)r3 * DIM + d]);
        acc += a0 + a1 + a2 + a3;
    }
    for (; i < s1; i += 8) acc += bf2f(Qn[(size_t)list[i] * DIM + d]);
    atomicAdd(&CS[c * DIM + d], acc);
}

// ---------- K3: bf16 MFMA GEMM tile + fused per-row partial stats --------------------
union SMemU { short bs[BN][72]; float sim[64][132]; };

__global__ __launch_bounds__(256) void k_gemm_fused(const unsigned short* __restrict__ Tn,
                                                    const unsigned short* __restrict__ Qn,
                                                    float* __restrict__ pse,   // [375][512]
                                                    float* __restrict__ pv5,   // [375][512][5]
                                                    int*   __restrict__ pi5) {
    __shared__ SMemU sm;
    const int bn = blockIdx.x, bm = blockIdx.y;
    const int t = threadIdx.x;
    const int wid = t >> 6, lane = t & 63;
    const int wr = wid >> 1, wc = wid & 1;
    const int c16 = lane & 15, g = lane >> 4;
    const int m0 = bm * BM, n0 = bn * BN;

    f32x4 acc[4][4];
#pragma unroll
    for (int m = 0; m < 4; ++m)
#pragma unroll
        for (int n = 0; n < 4; ++n) acc[m][n] = (f32x4){0.f, 0.f, 0.f, 0.f};

    const int sr = t >> 3;   // 0..31
    const int sg = t & 7;    // 16B segment

    for (int k0 = 0; k0 < DIM; k0 += BK) {
        __syncthreads();
#pragma unroll
        for (int i = 0; i < 4; ++i) {
            int r = sr + i * 32;
            *(uint4*)&sm.bs[r][sg * 8] =
                *(const uint4*)(Qn + (size_t)(n0 + r) * DIM + k0 + sg * 8);
        }
        __syncthreads();
#pragma unroll
        for (int kk = 0; kk < 2; ++kk) {
            bf16x8 aF[4], bF[4];
#pragma unroll
            for (int m = 0; m < 4; ++m)
                aF[m] = *(const bf16x8*)(Tn + (size_t)(m0 + wr * 64 + m * 16 + c16) * DIM
                                         + k0 + kk * 32 + g * 8);
#pragma unroll
            for (int n = 0; n < 4; ++n)
                bF[n] = *(const bf16x8*)&sm.bs[wc * 64 + n * 16 + c16][kk * 32 + g * 8];
#pragma unroll
            for (int m = 0; m < 4; ++m)
#pragma unroll
                for (int n = 0; n < 4; ++n)
                    acc[m][n] = __builtin_amdgcn_mfma_f32_16x16x32_bf16(aF[m], bF[n], acc[m][n], 0, 0, 0);
        }
    }

    // fused epilogue: two 64-row phases through LDS; one lane owns one row x 32 cols
    for (int ph = 0; ph < 2; ++ph) {
        __syncthreads();
        if (wr == ph) {
#pragma unroll
            for (int m = 0; m < 4; ++m)
#pragma unroll
                for (int n = 0; n < 4; ++n)
#pragma unroll
                    for (int j = 0; j < 4; ++j)
                        sm.sim[m * 16 + g * 4 + j][wc * 64 + n * 16 + c16] = acc[m][n][j];
        }
        __syncthreads();
        const int lrow = wid * 16 + c16;          // LDS row this lane scans
        float v[KNN]; int id[KNN];
#pragma unroll
        for (int q = 0; q < KNN; ++q) { v[q] = NEG_INF; id[q] = 0x7fffffff; }
        float se = 0.0f;
#pragma unroll
        for (int i = 0; i < 8; ++i) {
            float4 s4 = *(const float4*)&sm.sim[lrow][g * 32 + i * 4];
            float sv4[4] = {s4.x, s4.y, s4.z, s4.w};
#pragma unroll
            for (int e = 0; e < 4; ++e) {
                float s = sv4[e];
                int cg = n0 + g * 32 + i * 4 + e;
                se += __expf((s - 1.0f) * INV_TAU);
                if (s > v[KNN - 1] || (s == v[KNN - 1] && cg < id[KNN - 1])) {
                    v[KNN - 1] = s; id[KNN - 1] = cg;
#pragma unroll
                    for (int q = KNN - 1; q > 0; --q) {
                        bool sw = (v[q] > v[q - 1]) || (v[q] == v[q - 1] && id[q] < id[q - 1]);
                        if (sw) {
                            float tv = v[q]; v[q] = v[q - 1]; v[q - 1] = tv;
                            int ti = id[q]; id[q] = id[q - 1]; id[q - 1] = ti;
                        }
                    }
                }
            }
        }
        // merge the 4 col-segment lanes of this row: xor 16, then 32
#pragma unroll
        for (int half = 0; half < 2; ++half) {
            int dist = 16 << half;
            float ov[KNN]; int oi[KNN];
#pragma unroll
            for (int q = 0; q < KNN; ++q) { ov[q] = __shfl_xor(v[q], dist); oi[q] = __shfl_xor(id[q], dist); }
            se += __shfl_xor(se, dist);
            merge5(v, id, ov, oi);
        }
        if (g == 0) {
            int grow = m0 + ph * 64 + wid * 16 + c16;
            pse[(size_t)bn * BSZ + grow] = se;
#pragma unroll
            for (int q = 0; q < KNN; ++q) {
                pv5[((size_t)bn * BSZ + grow) * KNN + q] = v[q];
                pi5[((size_t)bn * BSZ + grow) * KNN + q] = id[q];
            }
        }
    }
}

// ---------- K4: merge 375 chunk partials per row -> lse, pseudo ----------------------
__global__ __launch_bounds__(128) void k_merge(const float* __restrict__ pse,
                                               const float* __restrict__ pv5,
                                               const int* __restrict__ pi5,
                                               const int* __restrict__ slab,
                                               const int* __restrict__ qlab,
                                               float* __restrict__ lse,
                                               int* __restrict__ pseudo) {
    const int row = blockIdx.x, t = threadIdx.x;
    float v[KNN]; int id[KNN];
#pragma unroll
    for (int q = 0; q < KNN; ++q) { v[q] = NEG_INF; id[q] = 0x7fffffff; }
    float se = 0.0f;
    for (int c = t; c < NCHUNK; c += 128) {
        se += pse[(size_t)c * BSZ + row];
        float lv[KNN]; int li[KNN];
#pragma unroll
        for (int q = 0; q < KNN; ++q) {
            lv[q] = pv5[((size_t)c * BSZ + row) * KNN + q];
            li[q] = pi5[((size_t)c * BSZ + row) * KNN + q];
        }
        merge5(v, id, lv, li);
    }
#pragma unroll
    for (int dist = 1; dist <= 32; dist <<= 1) {
        float ov[KNN]; int oi[KNN];
#pragma unroll
        for (int q = 0; q < KNN; ++q) { ov[q] = __shfl_xor(v[q], dist); oi[q] = __shfl_xor(id[q], dist); }
        se += __shfl_xor(se, dist);
        merge5(v, id, ov, oi);
    }
    __shared__ float sv[2][KNN]; __shared__ int si[2][KNN]; __shared__ float ssum[2];
    if ((t & 63) == 0) {
        int w = t >> 6;
        ssum[w] = se;
#pragma unroll
        for (int q = 0; q < KNN; ++q) { sv[w][q] = v[q]; si[w][q] = id[q]; }
    }
    __syncthreads();
    if (t == 0) {
        float av[KNN], bv2[KNN]; int ai[KNN], bi2[KNN];
#pragma unroll
        for (int q = 0; q < KNN; ++q) {
            av[q] = sv[0][q]; ai[q] = si[0][q];
            bv2[q] = sv[1][q]; bi2[q] = si[1][q];
        }
        merge5(av, ai, bv2, bi2);
        float tot = ssum[0] + ssum[1];
        int lab[KNN];
#pragma unroll
        for (int q = 0; q < KNN; ++q) {
            int j = ai[q];
            lab[q] = (j < BSZ) ? slab[j] : qlab[j];
        }
        int bestc = 0, bestl = 0x7fffffff;
#pragma unroll
        for (int q = 0; q < KNN; ++q) {
            int c2 = 0;
#pragma unroll
            for (int w = 0; w < KNN; ++w) c2 += (lab[w] == lab[q]) ? 1 : 0;
            if (c2 > bestc || (c2 == bestc && lab[q] < bestl)) { bestc = c2; bestl = lab[q]; }
        }
        pseudo[row] = bestl;
        lse[row] = logf(tot) + INV_TAU;
    }
}

// ---------- K5: per-row loss via S = Tn[row] . CS[pseudo] ----------------------------
__global__ __launch_bounds__(256) void k_loss(const unsigned short* __restrict__ Tn,
                                              const float* __restrict__ CS,
                                              const int* __restrict__ cnt,
                                              const float* __restrict__ lse,
                                              const int* __restrict__ pseudo,
                                              float* __restrict__ rowloss) {
    int row  = blockIdx.x * 4 + (threadIdx.x >> 6);
    int lane = threadIdx.x & 63;
    int ps = pseudo[row];
    ushort4 tv = *(const ushort4*)(Tn + (size_t)row * DIM + lane * 4);
    float4  cv = *(const float4*)(CS + (size_t)ps * DIM + lane * 4);
    float d = bf2f(tv.x) * cv.x + bf2f(tv.y) * cv.y + bf2f(tv.z) * cv.z + bf2f(tv.w) * cv.w;
#pragma unroll
    for (int off = 32; off; off >>= 1) d += __shfl_down(d, off);
    if (lane == 0) {
        float pc = (float)cnt[ps];
        rowloss[row] = -(d * INV_TAU - pc * lse[row]) / fmaxf(pc, 1.0f);
    }
}

// ---------- K6: final reduction -------------------------------------------------------
__global__ __launch_bounds__(256) void k_final(const float* __restrict__ rowloss,
                                               const int* __restrict__ itp,
                                               float* __restrict__ out) {
    __shared__ float red[256];
    int t = threadIdx.x;
    red[t] = rowloss[t] + rowloss[t + 256];
    __syncthreads();
    for (int k = 128; k; k >>= 1) {
        if (t < k) red[t] += red[t + k];
        __syncthreads();
    }
    if (t == 0) out[0] = ((itp[0] > WARM) ? COEFF_V : 0.0f) * (red[0] / (float)BSZ);
}

// ---------- launcher ------------------------------------------------------------------
extern "C" void kernel_launch(void* const* d_in, const int* in_sizes, int n_in,
                              void* d_out, int out_size, void* d_ws, size_t ws_size,
                              hipStream_t stream) {
    const float* feat  = (const float*)d_in[0];
    const int*   slab  = (const int*)d_in[1];
    const int*   itp   = (const int*)d_in[2];
    const float* queue = (const float*)d_in[3];
    const int*   qlab  = (const int*)d_in[4];
    float* out = (float*)d_out;

    char* ws = (char*)d_ws;
    unsigned short* Qn = (unsigned short*)(ws);            // 24,576,000
    unsigned short* Tn = (unsigned short*)(ws + 24576000); //    262,144
    float* CS      = (float*)(ws + 24838144);              //    129,024
    int*   cnt     = (int*)  (ws + 24967168);              //        512
    int*   cnt2    = (int*)  (ws + 24967680);              //        512
    int*   off     = (int*)  (ws + 24968192);              //        512
    int*   list    = (int*)  (ws + 24968704);              //    192,000
    float* pse     = (float*)(ws + 25160704);              //    768,000
    float* pv5     = (float*)(ws + 25928704);              //  3,840,000
    int*   pi5     = (int*)  (ws + 29768704);              //  3,840,000
    float* lse     = (float*)(ws + 33608704);              //      2,048
    int*   pseudo  = (int*)  (ws + 33610752);              //      2,048
    float* rowloss = (float*)(ws + 33612800);              //      2,048

    hipLaunchKernelGGL(k_prep, dim3((BSZ + NQ + 3) / 4), dim3(256), 0, stream, feat, queue, Tn, Qn);
    hipLaunchKernelGGL(k_zero, dim3(126), dim3(256), 0, stream, CS, cnt, cnt2);
    hipLaunchKernelGGL(k_hist, dim3((NQ + 255) / 256), dim3(256), 0, stream, slab, qlab, cnt);
    hipLaunchKernelGGL(k_prefix, dim3(1), dim3(64), 0, stream, cnt, off);
    hipLaunchKernelGGL(k_scatter, dim3((NQ + 255) / 256), dim3(256), 0, stream, slab, qlab, off, cnt2, list);
    hipLaunchKernelGGL(k_cs2, dim3(NCLS, 8), dim3(256), 0, stream, Qn, off, list, CS);
    hipLaunchKernelGGL(k_gemm_fused, dim3(NCHUNK, BSZ / BM), dim3(256), 0, stream, Tn, Qn, pse, pv5, pi5);
    hipLaunchKernelGGL(k_merge, dim3(BSZ), dim3(128), 0, stream, pse, pv5, pi5, slab, qlab, lse, pseudo);
    hipLaunchKernelGGL(k_loss, dim3(BSZ / 4), dim3(256), 0, stream, Tn, CS, cnt, lse, pseudo, rowloss);
    hipLaunchKernelGGL(k_final, dim3(1), dim3(256), 0, stream, rowloss, itp, out);
}

// Round 4
// 207.240 us; speedup vs baseline: 1.7862x; 1.3191x over previous
//
#include <hip/hip_runtime.h>
#include <math.h>

#define DIM 256
#define NQ 48000
#define NCLS 126
#define BSZ 512
#define KNN 5
#define INV_TAU 14.285714285714286f
#define COEFF_V 0.1f
#define WARM 4000
#define NCH 750              /* 64-wide q chunks */
#define NEG_INF -3.402823466e38f

typedef __attribute__((ext_vector_type(8))) short bf16x8;
typedef __attribute__((ext_vector_type(4))) float f32x4;

__device__ __forceinline__ unsigned short f2bf(float f) {
    unsigned u = __float_as_uint(f);
    u += 0x7fffu + ((u >> 16) & 1u);
    return (unsigned short)(u >> 16);
}
__device__ __forceinline__ float bf2f(unsigned short h) {
    return __uint_as_float(((unsigned)h) << 16);
}

// branchless top-5 merge, compile-time indices only
__device__ __forceinline__ void merge5(float (&av)[KNN], int (&ai)[KNN],
                                       float (&bv)[KNN], int (&bi)[KNN]) {
    float rv[KNN]; int ri[KNN];
#pragma unroll
    for (int q = 0; q < KNN; ++q) {
        bool ta = (av[0] > bv[0]) || (av[0] == bv[0] && ai[0] < bi[0]);
        rv[q] = ta ? av[0] : bv[0];
        ri[q] = ta ? ai[0] : bi[0];
        if (q < KNN - 1) {
#pragma unroll
            for (int i = 0; i < KNN - 1; ++i) {
                float sav = av[i + 1], sbv = bv[i + 1];
                int   sai = ai[i + 1], sbi = bi[i + 1];
                av[i] = ta ? sav : av[i];  ai[i] = ta ? sai : ai[i];
                bv[i] = ta ? bv[i] : sbv;  bi[i] = ta ? bi[i] : sbi;
            }
        }
    }
#pragma unroll
    for (int q = 0; q < KNN; ++q) { av[q] = rv[q]; ai[q] = ri[q]; }
}

// ---------- K0: normalize + bf16 pack ------------------------------------------------
__global__ __launch_bounds__(256) void k_prep(const float* __restrict__ feat,
                                              const float* __restrict__ queue,
                                              unsigned short* __restrict__ Tn,
                                              unsigned short* __restrict__ Qn) {
    int row  = blockIdx.x * 4 + (threadIdx.x >> 6);
    int lane = threadIdx.x & 63;
    if (row >= BSZ + NQ) return;
    const float* src;
    unsigned short* dst;
    if (row < BSZ) { src = feat + (size_t)(BSZ + row) * DIM; dst = Tn + (size_t)row * DIM; }
    else {
        int q = row - BSZ;
        src = (q < BSZ) ? feat + (size_t)q * DIM : queue + (size_t)q * DIM;
        dst = Qn + (size_t)q * DIM;
    }
    float4 v = ((const float4*)src)[lane];
    float ss = v.x * v.x + v.y * v.y + v.z * v.z + v.w * v.w;
#pragma unroll
    for (int off = 32; off; off >>= 1) ss += __shfl_xor(ss, off);
    float inv = 1.0f / fmaxf(sqrtf(ss), 1e-12f);
    ushort4 o = make_ushort4(f2bf(v.x * inv), f2bf(v.y * inv), f2bf(v.z * inv), f2bf(v.w * inv));
    *(ushort4*)(dst + lane * 4) = o;
}

// ---------- zero scratch -------------------------------------------------------------
__global__ __launch_bounds__(256) void k_zero(float* __restrict__ CS,
                                              int* __restrict__ cnt,
                                              int* __restrict__ cnt2) {
    int i = blockIdx.x * 256 + threadIdx.x;
    if (i < NCLS * DIM) CS[i] = 0.0f;
    if (i < NCLS) { cnt[i] = 0; cnt2[i] = 0; }
}

// ---------- label histogram ----------------------------------------------------------
__global__ __launch_bounds__(256) void k_hist(const int* __restrict__ slab,
                                              const int* __restrict__ qlab,
                                              int* __restrict__ cnt) {
    int r = blockIdx.x * 256 + threadIdx.x;
    if (r < NQ) {
        int lb = (r < BSZ) ? slab[r] : qlab[r];
        atomicAdd(&cnt[lb], 1);
    }
}

// ---------- exclusive prefix over 126 classes ----------------------------------------
__global__ void k_prefix(const int* __restrict__ cnt, int* __restrict__ off) {
    if (threadIdx.x == 0) {
        int acc = 0;
        for (int c = 0; c < NCLS; ++c) { off[c] = acc; acc += cnt[c]; }
        off[NCLS] = acc;
    }
}

// ---------- scatter row ids into per-class lists -------------------------------------
__global__ __launch_bounds__(256) void k_scatter(const int* __restrict__ slab,
                                                 const int* __restrict__ qlab,
                                                 const int* __restrict__ off,
                                                 int* __restrict__ cnt2,
                                                 int* __restrict__ list) {
    int r = blockIdx.x * 256 + threadIdx.x;
    if (r < NQ) {
        int lb = (r < BSZ) ? slab[r] : qlab[r];
        int idx = atomicAdd(&cnt2[lb], 1);
        list[off[lb] + idx] = r;
    }
}

// ---------- per-class feature sums ---------------------------------------------------
__global__ __launch_bounds__(256) void k_cs2(const unsigned short* __restrict__ Qn,
                                             const int* __restrict__ off,
                                             const int* __restrict__ list,
                                             float* __restrict__ CS) {
    const int c = blockIdx.x;
    const int part = blockIdx.y;   // 0..7
    const int d = threadIdx.x;
    const int s1 = off[c + 1];
    float acc = 0.0f;
    int i = off[c] + part;
    for (; i + 24 < s1; i += 32) {
        int r0 = list[i], r1 = list[i + 8], r2 = list[i + 16], r3 = list[i + 24];
        float a0 = bf2f(Qn[(size_t)r0 * DIM + d]);
        float a1 = bf2f(Qn[(size_t)r1 * DIM + d]);
        float a2 = bf2f(Qn[(size_t)r2 * DIM + d]);
        float a3 = bf2f(Qn[(size_t)r3 * DIM + d]);
        acc += a0 + a1 + a2 + a3;
    }
    for (; i < s1; i += 8) acc += bf2f(Qn[(size_t)list[i] * DIM + d]);
    atomicAdd(&CS[c * DIM + d], acc);
}

// ---------- K3: swapped-operand MFMA, register-only epilogue -------------------------
// Wave W: qc = W>>3 (64-q chunk), tc = W&7 (64-t chunk). A = Qn rows, B = Tn rows.
// acc[mq][nt][j] = sim[t = tc*64+nt*16+c16][q = qc*64+mq*16+g*4+j].
// Per (t-row, chunk): emit sumexp and chunk-max. No LDS, no barriers, no top-5.
__global__ __launch_bounds__(256) void k_gemm2(const unsigned short* __restrict__ Tn,
                                               const unsigned short* __restrict__ Qn,
                                               float* __restrict__ pse,    // [512][750]
                                               float* __restrict__ pmax) { // [512][750]
    const int t = threadIdx.x;
    const int wid = t >> 6, lane = t & 63;
    const int W = blockIdx.x * 4 + wid;
    const int qc = W >> 3;
    const int tc = W & 7;
    const int c16 = lane & 15, g = lane >> 4;

    f32x4 acc[4][4];
#pragma unroll
    for (int a = 0; a < 4; ++a)
#pragma unroll
        for (int b = 0; b < 4; ++b) acc[a][b] = (f32x4){0.f, 0.f, 0.f, 0.f};

    const unsigned short* Abase = Qn + (size_t)(qc * 64 + c16) * DIM + g * 8;
    const unsigned short* Bbase = Tn + (size_t)(tc * 64 + c16) * DIM + g * 8;

#pragma unroll
    for (int ks = 0; ks < 8; ++ks) {       // 8 K-slices of 32
        bf16x8 aF[4], bF[4];
#pragma unroll
        for (int mq = 0; mq < 4; ++mq)
            aF[mq] = *(const bf16x8*)(Abase + (size_t)mq * 16 * DIM + ks * 32);
#pragma unroll
        for (int nt = 0; nt < 4; ++nt)
            bF[nt] = *(const bf16x8*)(Bbase + (size_t)nt * 16 * DIM + ks * 32);
#pragma unroll
        for (int mq = 0; mq < 4; ++mq)
#pragma unroll
            for (int nt = 0; nt < 4; ++nt)
                acc[mq][nt] = __builtin_amdgcn_mfma_f32_16x16x32_bf16(aF[mq], bF[nt], acc[mq][nt], 0, 0, 0);
    }

#pragma unroll
    for (int nt = 0; nt < 4; ++nt) {
        float se = 0.0f, mx = NEG_INF;
#pragma unroll
        for (int mq = 0; mq < 4; ++mq)
#pragma unroll
            for (int j = 0; j < 4; ++j) {
                float s = acc[mq][nt][j];
                se += __expf((s - 1.0f) * INV_TAU);
                mx = fmaxf(mx, s);
            }
        se += __shfl_xor(se, 16); se += __shfl_xor(se, 32);
        mx = fmaxf(mx, __shfl_xor(mx, 16)); mx = fmaxf(mx, __shfl_xor(mx, 32));
        if (g == 0) {
            int tr = tc * 64 + nt * 16 + c16;
            pse[(size_t)tr * NCH + qc]  = se;
            pmax[(size_t)tr * NCH + qc] = mx;
        }
    }
}

// ---------- K4: per-row: lse + top-5 candidate chunks --------------------------------
__global__ __launch_bounds__(64) void k_merge2(const float* __restrict__ pse,
                                               const float* __restrict__ pmax,
                                               float* __restrict__ lse,
                                               int* __restrict__ cand) {
    const int row = blockIdx.x, lane = threadIdx.x;
    float se = 0.0f;
    float v[KNN]; int id[KNN];
#pragma unroll
    for (int q = 0; q < KNN; ++q) { v[q] = NEG_INF; id[q] = 0x7fffffff; }
    for (int c = lane; c < NCH; c += 64) {
        se += pse[(size_t)row * NCH + c];
        float s = pmax[(size_t)row * NCH + c];
        if (s > v[KNN - 1] || (s == v[KNN - 1] && c < id[KNN - 1])) {
            v[KNN - 1] = s; id[KNN - 1] = c;
#pragma unroll
            for (int q = KNN - 1; q > 0; --q) {
                bool sw = (v[q] > v[q - 1]) || (v[q] == v[q - 1] && id[q] < id[q - 1]);
                if (sw) {
                    float tv = v[q]; v[q] = v[q - 1]; v[q - 1] = tv;
                    int ti = id[q]; id[q] = id[q - 1]; id[q - 1] = ti;
                }
            }
        }
    }
#pragma unroll
    for (int dist = 1; dist <= 32; dist <<= 1) {
        float ov[KNN]; int oi[KNN];
#pragma unroll
        for (int q = 0; q < KNN; ++q) { ov[q] = __shfl_xor(v[q], dist); oi[q] = __shfl_xor(id[q], dist); }
        se += __shfl_xor(se, dist);
        merge5(v, id, ov, oi);
    }
    if (lane == 0) {
        lse[row] = logf(se) + INV_TAU;
#pragma unroll
        for (int q = 0; q < KNN; ++q) cand[row * KNN + q] = id[q];
    }
}

// ---------- K5: exact top-5 within candidate chunks -> pseudo label ------------------
__global__ __launch_bounds__(320) void k_rescan(const unsigned short* __restrict__ Tn,
                                                const unsigned short* __restrict__ Qn,
                                                const int* __restrict__ cand,
                                                const int* __restrict__ slab,
                                                const int* __restrict__ qlab,
                                                int* __restrict__ pseudo) {
    const int row = blockIdx.x, t = threadIdx.x;
    __shared__ float tn_sh[DIM];
    __shared__ int c5[KNN];
    __shared__ float rv[5]; __shared__ int rq[5];
    __shared__ int winq, t5s[KNN];
    if (t < DIM) tn_sh[t] = bf2f(Tn[(size_t)row * DIM + t]);
    if (t < KNN) c5[t] = cand[row * KNN + t];
    __syncthreads();
    const int q = c5[t >> 6] * 64 + (t & 63);
    float v = 0.0f;
    for (int d = 0; d < DIM; d += 8) {
        bf16x8 qv = *(const bf16x8*)(Qn + (size_t)q * DIM + d);
#pragma unroll
        for (int e = 0; e < 8; ++e)
            v = fmaf(bf2f((unsigned short)qv[e]), tn_sh[d + e], v);
    }
    for (int k = 0; k < KNN; ++k) {
        float vv = v; int qq = q;
#pragma unroll
        for (int d2 = 1; d2 <= 32; d2 <<= 1) {
            float ov = __shfl_xor(vv, d2); int oq = __shfl_xor(qq, d2);
            bool bet = (ov > vv) || (ov == vv && oq < qq);
            vv = bet ? ov : vv; qq = bet ? oq : qq;
        }
        if ((t & 63) == 0) { rv[t >> 6] = vv; rq[t >> 6] = qq; }
        __syncthreads();
        if (t == 0) {
            float bv = rv[0]; int bq = rq[0];
            for (int w = 1; w < 5; ++w) {
                bool bet = (rv[w] > bv) || (rv[w] == bv && rq[w] < bq);
                if (bet) { bv = rv[w]; bq = rq[w]; }
            }
            winq = bq; t5s[k] = bq;
        }
        __syncthreads();
        if (q == winq) v = NEG_INF;
        __syncthreads();
    }
    if (t == 0) {
        int lab[KNN];
#pragma unroll
        for (int k = 0; k < KNN; ++k) {
            int j = t5s[k];
            lab[k] = (j < BSZ) ? slab[j] : qlab[j];
        }
        int bestc = 0, bestl = 0x7fffffff;
#pragma unroll
        for (int k = 0; k < KNN; ++k) {
            int c2 = 0;
#pragma unroll
            for (int w = 0; w < KNN; ++w) c2 += (lab[w] == lab[k]) ? 1 : 0;
            if (c2 > bestc || (c2 == bestc && lab[k] < bestl)) { bestc = c2; bestl = lab[k]; }
        }
        pseudo[row] = bestl;
    }
}

// ---------- K6: per-row loss ---------------------------------------------------------
__global__ __launch_bounds__(256) void k_loss(const unsigned short* __restrict__ Tn,
                                              const float* __restrict__ CS,
                                              const int* __restrict__ cnt,
                                              const float* __restrict__ lse,
                                              const int* __restrict__ pseudo,
                                              float* __restrict__ rowloss) {
    int row  = blockIdx.x * 4 + (threadIdx.x >> 6);
    int lane = threadIdx.x & 63;
    int ps = pseudo[row];
    ushort4 tv = *(const ushort4*)(Tn + (size_t)row * DIM + lane * 4);
    float4  cv = *(const float4*)(CS + (size_t)ps * DIM + lane * 4);
    float d = bf2f(tv.x) * cv.x + bf2f(tv.y) * cv.y + bf2f(tv.z) * cv.z + bf2f(tv.w) * cv.w;
#pragma unroll
    for (int off = 32; off; off >>= 1) d += __shfl_down(d, off);
    if (lane == 0) {
        float pc = (float)cnt[ps];
        rowloss[row] = -(d * INV_TAU - pc * lse[row]) / fmaxf(pc, 1.0f);
    }
}

// ---------- K7: final reduction -------------------------------------------------------
__global__ __launch_bounds__(256) void k_final(const float* __restrict__ rowloss,
                                               const int* __restrict__ itp,
                                               float* __restrict__ out) {
    __shared__ float red[256];
    int t = threadIdx.x;
    red[t] = rowloss[t] + rowloss[t + 256];
    __syncthreads();
    for (int k = 128; k; k >>= 1) {
        if (t < k) red[t] += red[t + k];
        __syncthreads();
    }
    if (t == 0) out[0] = ((itp[0] > WARM) ? COEFF_V : 0.0f) * (red[0] / (float)BSZ);
}

// ---------- launcher ------------------------------------------------------------------
extern "C" void kernel_launch(void* const* d_in, const int* in_sizes, int n_in,
                              void* d_out, int out_size, void* d_ws, size_t ws_size,
                              hipStream_t stream) {
    const float* feat  = (const float*)d_in[0];
    const int*   slab  = (const int*)d_in[1];
    const int*   itp   = (const int*)d_in[2];
    const float* queue = (const float*)d_in[3];
    const int*   qlab  = (const int*)d_in[4];
    float* out = (float*)d_out;

    char* ws = (char*)d_ws;
    unsigned short* Qn = (unsigned short*)(ws);            // 24,576,000
    unsigned short* Tn = (unsigned short*)(ws + 24576000); //    262,144
    float* CS      = (float*)(ws + 24838144);              //    129,024
    int*   cnt     = (int*)  (ws + 24967168);              //        512
    int*   cnt2    = (int*)  (ws + 24967680);              //        512
    int*   off     = (int*)  (ws + 24968192);              //        512
    int*   list    = (int*)  (ws + 24968704);              //    192,000
    float* pse     = (float*)(ws + 25160704);              //  1,536,000
    float* pmax    = (float*)(ws + 26696704);              //  1,536,000
    float* lse     = (float*)(ws + 28232704);              //      2,048
    int*   cand    = (int*)  (ws + 28234752);              //     10,240
    int*   pseudo  = (int*)  (ws + 28244992);              //      2,048
    float* rowloss = (float*)(ws + 28247040);              //      2,048

    hipLaunchKernelGGL(k_prep, dim3((BSZ + NQ + 3) / 4), dim3(256), 0, stream, feat, queue, Tn, Qn);
    hipLaunchKernelGGL(k_zero, dim3(126), dim3(256), 0, stream, CS, cnt, cnt2);
    hipLaunchKernelGGL(k_hist, dim3((NQ + 255) / 256), dim3(256), 0, stream, slab, qlab, cnt);
    hipLaunchKernelGGL(k_prefix, dim3(1), dim3(64), 0, stream, cnt, off);
    hipLaunchKernelGGL(k_scatter, dim3((NQ + 255) / 256), dim3(256), 0, stream, slab, qlab, off, cnt2, list);
    hipLaunchKernelGGL(k_cs2, dim3(NCLS, 8), dim3(256), 0, stream, Qn, off, list, CS);
    hipLaunchKernelGGL(k_gemm2, dim3(1500), dim3(256), 0, stream, Tn, Qn, pse, pmax);
    hipLaunchKernelGGL(k_merge2, dim3(BSZ), dim3(64), 0, stream, pse, pmax, lse, cand);
    hipLaunchKernelGGL(k_rescan, dim3(BSZ), dim3(320), 0, stream, Tn, Qn, cand, slab, qlab, pseudo);
    hipLaunchKernelGGL(k_loss, dim3(BSZ / 4), dim3(256), 0, stream, Tn, CS, cnt, lse, pseudo, rowloss);
    hipLaunchKernelGGL(k_final, dim3(1), dim3(256), 0, stream, rowloss, itp, out);
}

// Round 5
// 135.731 us; speedup vs baseline: 2.7273x; 1.5268x over previous
//
#include <hip/hip_runtime.h>
#include <math.h>

#define DIM 256
#define NQ 48000
#define NCLS 126
#define BSZ 512
#define KNN 5
#define INV_TAU 14.285714285714286f
#define COEFF_V 0.1f
#define WARM 4000
#define NCH 750              /* 64-wide q chunks */
#define NEG_INF -3.402823466e38f

typedef __attribute__((ext_vector_type(8))) short bf16x8;
typedef __attribute__((ext_vector_type(4))) float f32x4;

__device__ __forceinline__ unsigned short f2bf(float f) {
    unsigned u = __float_as_uint(f);
    u += 0x7fffu + ((u >> 16) & 1u);
    return (unsigned short)(u >> 16);
}
__device__ __forceinline__ float bf2f(unsigned short h) {
    return __uint_as_float(((unsigned)h) << 16);
}

// fragment-tiled layout: 16-row x 32-col tiles of 1KB; within a tile, the 64
// 16B segments are laid out so a wave's MFMA fragment load is one dense tile.
// element (r,d) -> [(r>>4)*8 + (d>>5)]*512 + [(r&15)*4 + ((d>>3)&3)]*8 + (d&7)
__device__ __forceinline__ size_t tidx(int r, int d) {
    return ((size_t)((r >> 4) * 8 + (d >> 5)) << 9)
         + (size_t)(((r & 15) * 4 + ((d >> 3) & 3)) << 3)
         + (size_t)(d & 7);
}

// branchless top-5 merge, compile-time indices only
__device__ __forceinline__ void merge5(float (&av)[KNN], int (&ai)[KNN],
                                       float (&bv)[KNN], int (&bi)[KNN]) {
    float rv[KNN]; int ri[KNN];
#pragma unroll
    for (int q = 0; q < KNN; ++q) {
        bool ta = (av[0] > bv[0]) || (av[0] == bv[0] && ai[0] < bi[0]);
        rv[q] = ta ? av[0] : bv[0];
        ri[q] = ta ? ai[0] : bi[0];
        if (q < KNN - 1) {
#pragma unroll
            for (int i = 0; i < KNN - 1; ++i) {
                float sav = av[i + 1], sbv = bv[i + 1];
                int   sai = ai[i + 1], sbi = bi[i + 1];
                av[i] = ta ? sav : av[i];  ai[i] = ta ? sai : ai[i];
                bv[i] = ta ? bv[i] : sbv;  bi[i] = ta ? bi[i] : sbi;
            }
        }
    }
#pragma unroll
    for (int q = 0; q < KNN; ++q) { av[q] = rv[q]; ai[q] = ri[q]; }
}

// per-thread sorted-desc insert of (s, idx)
__device__ __forceinline__ void ins5(float (&v)[KNN], int (&id)[KNN], float s, int jj) {
    if (s > v[KNN - 1] || (s == v[KNN - 1] && jj < id[KNN - 1])) {
        v[KNN - 1] = s; id[KNN - 1] = jj;
#pragma unroll
        for (int q = KNN - 1; q > 0; --q) {
            bool sw = (v[q] > v[q - 1]) || (v[q] == v[q - 1] && id[q] < id[q - 1]);
            if (sw) {
                float tv = v[q]; v[q] = v[q - 1]; v[q - 1] = tv;
                int ti = id[q]; id[q] = id[q - 1]; id[q - 1] = ti;
            }
        }
    }
}

// ---------- K0: normalize + bf16 pack into fragment-tiled layout ---------------------
__global__ __launch_bounds__(256) void k_prep(const float* __restrict__ feat,
                                              const float* __restrict__ queue,
                                              unsigned short* __restrict__ Tt,
                                              unsigned short* __restrict__ Qt) {
    int row  = blockIdx.x * 4 + (threadIdx.x >> 6);
    int lane = threadIdx.x & 63;
    if (row >= BSZ + NQ) return;
    const float* src;
    unsigned short* dst;
    int r;
    if (row < BSZ) { src = feat + (size_t)(BSZ + row) * DIM; dst = Tt; r = row; }
    else {
        int q = row - BSZ;
        src = (q < BSZ) ? feat + (size_t)q * DIM : queue + (size_t)q * DIM;
        dst = Qt; r = q;
    }
    float4 v = ((const float4*)src)[lane];
    float ss = v.x * v.x + v.y * v.y + v.z * v.z + v.w * v.w;
#pragma unroll
    for (int off = 32; off; off >>= 1) ss += __shfl_xor(ss, off);
    float inv = 1.0f / fmaxf(sqrtf(ss), 1e-12f);
    ushort4 o = make_ushort4(f2bf(v.x * inv), f2bf(v.y * inv), f2bf(v.z * inv), f2bf(v.w * inv));
    *(ushort4*)(dst + tidx(r, lane * 4)) = o;
}

// ---------- K1: single-block counting sort (hist + prefix + scatter) + CS zero -------
__global__ __launch_bounds__(1024) void k_sort(const int* __restrict__ slab,
                                               const int* __restrict__ qlab,
                                               int* __restrict__ cnt,
                                               int* __restrict__ off,
                                               int* __restrict__ list,
                                               float* __restrict__ CS) {
    __shared__ int h[NCLS], o[NCLS + 1];
    const int t = threadIdx.x;
    for (int i = t; i < NCLS * DIM; i += 1024) CS[i] = 0.0f;
    if (t < NCLS) h[t] = 0;
    __syncthreads();
    for (int r = t; r < NQ; r += 1024) {
        int lb = (r < BSZ) ? slab[r] : qlab[r];
        atomicAdd(&h[lb], 1);
    }
    __syncthreads();
    if (t == 0) {
        int a = 0;
        for (int c = 0; c < NCLS; ++c) { o[c] = a; a += h[c]; }
        o[NCLS] = a;
    }
    __syncthreads();
    if (t < NCLS) { cnt[t] = h[t]; off[t] = o[t]; h[t] = o[t]; }
    if (t == 0) off[NCLS] = o[NCLS];
    __syncthreads();
    for (int r = t; r < NQ; r += 1024) {
        int lb = (r < BSZ) ? slab[r] : qlab[r];
        int idx = atomicAdd(&h[lb], 1);
        list[idx] = r;
    }
}

// ---------- K2: per-class feature sums (tiled reads) ---------------------------------
__global__ __launch_bounds__(256) void k_cs2(const unsigned short* __restrict__ Qt,
                                             const int* __restrict__ off,
                                             const int* __restrict__ list,
                                             float* __restrict__ CS) {
    const int c = blockIdx.x;
    const int part = blockIdx.y;   // 0..7
    const int d = threadIdx.x;
    const int s1 = off[c + 1];
    float acc = 0.0f;
    int i = off[c] + part;
    for (; i + 24 < s1; i += 32) {
        int r0 = list[i], r1 = list[i + 8], r2 = list[i + 16], r3 = list[i + 24];
        float a0 = bf2f(Qt[tidx(r0, d)]);
        float a1 = bf2f(Qt[tidx(r1, d)]);
        float a2 = bf2f(Qt[tidx(r2, d)]);
        float a3 = bf2f(Qt[tidx(r3, d)]);
        acc += a0 + a1 + a2 + a3;
    }
    for (; i < s1; i += 8) acc += bf2f(Qt[tidx(list[i], d)]);
    atomicAdd(&CS[c * DIM + d], acc);
}

// ---------- K3: swapped-operand MFMA from tiled layout, register-only epilogue -------
// Wave W: qc = W>>3 (64-q chunk), tc = W&7 (64-t chunk).
// acc[mq][nt][j] = sim[t = tc*64+nt*16+c16][q = qc*64+mq*16+g*4+j].
__global__ __launch_bounds__(256) void k_gemm2(const unsigned short* __restrict__ Tt,
                                               const unsigned short* __restrict__ Qt,
                                               float* __restrict__ pse,    // [512][750]
                                               float* __restrict__ pmax) { // [512][750]
    const int t = threadIdx.x;
    const int wid = t >> 6, lane = t & 63;
    const int W = blockIdx.x * 4 + wid;
    const int qc = W >> 3;
    const int tc = W & 7;
    const int c16 = lane & 15, g = lane >> 4;
    const int lseg = (c16 * 4 + g) * 8;   // this lane's 16B segment within any tile

    f32x4 acc[4][4];
#pragma unroll
    for (int a = 0; a < 4; ++a)
#pragma unroll
        for (int b = 0; b < 4; ++b) acc[a][b] = (f32x4){0.f, 0.f, 0.f, 0.f};

    const unsigned short* Ab = Qt + ((size_t)(qc * 4) << 12) + lseg;  // *8*512
    const unsigned short* Bb = Tt + ((size_t)(tc * 4) << 12) + lseg;

#pragma unroll
    for (int ks = 0; ks < 8; ++ks) {       // 8 K-slices of 32
        bf16x8 aF[4], bF[4];
#pragma unroll
        for (int mq = 0; mq < 4; ++mq)
            aF[mq] = *(const bf16x8*)(Ab + (size_t)((mq * 8 + ks) << 9));
#pragma unroll
        for (int nt = 0; nt < 4; ++nt)
            bF[nt] = *(const bf16x8*)(Bb + (size_t)((nt * 8 + ks) << 9));
#pragma unroll
        for (int mq = 0; mq < 4; ++mq)
#pragma unroll
            for (int nt = 0; nt < 4; ++nt)
                acc[mq][nt] = __builtin_amdgcn_mfma_f32_16x16x32_bf16(aF[mq], bF[nt], acc[mq][nt], 0, 0, 0);
    }

#pragma unroll
    for (int nt = 0; nt < 4; ++nt) {
        float se = 0.0f, mx = NEG_INF;
#pragma unroll
        for (int mq = 0; mq < 4; ++mq)
#pragma unroll
            for (int j = 0; j < 4; ++j) {
                float s = acc[mq][nt][j];
                se += __expf((s - 1.0f) * INV_TAU);
                mx = fmaxf(mx, s);
            }
        se += __shfl_xor(se, 16); se += __shfl_xor(se, 32);
        mx = fmaxf(mx, __shfl_xor(mx, 16)); mx = fmaxf(mx, __shfl_xor(mx, 32));
        if (g == 0) {
            int tr = tc * 64 + nt * 16 + c16;
            pse[(size_t)tr * NCH + qc]  = se;
            pmax[(size_t)tr * NCH + qc] = mx;
        }
    }
}

// ---------- K4: fused tail — chunk merge, rescan, vote, per-row loss -----------------
__global__ __launch_bounds__(320) void k_tail(const unsigned short* __restrict__ Tt,
                                              const unsigned short* __restrict__ Qt,
                                              const float* __restrict__ pse,
                                              const float* __restrict__ pmax,
                                              const float* __restrict__ CS,
                                              const int* __restrict__ cnt,
                                              const int* __restrict__ slab,
                                              const int* __restrict__ qlab,
                                              float* __restrict__ rowloss) {
    const int row = blockIdx.x, t = threadIdx.x;
    __shared__ float tn_sh[DIM];
    __shared__ float wse[5];
    __shared__ float wv[5][KNN]; __shared__ int wi[5][KNN];
    __shared__ int c5[KNN];
    __shared__ float s_lse;
    __shared__ float rv[5]; __shared__ int rq[5];
    __shared__ int winq, t5s[KNN], s_ps;
    __shared__ float dred[5];

    if (t < DIM) tn_sh[t] = bf2f(Tt[tidx(row, t)]);

    // ---- phase 1: merge 750 chunk stats -> lse + top-5 candidate chunks
    float v[KNN]; int id[KNN];
#pragma unroll
    for (int q = 0; q < KNN; ++q) { v[q] = NEG_INF; id[q] = 0x7fffffff; }
    float se = 0.0f;
    for (int c = t; c < NCH; c += 320) {
        se += pse[(size_t)row * NCH + c];
        ins5(v, id, pmax[(size_t)row * NCH + c], c);
    }
#pragma unroll
    for (int dist = 1; dist <= 32; dist <<= 1) {
        float ov[KNN]; int oi[KNN];
#pragma unroll
        for (int q = 0; q < KNN; ++q) { ov[q] = __shfl_xor(v[q], dist); oi[q] = __shfl_xor(id[q], dist); }
        se += __shfl_xor(se, dist);
        merge5(v, id, ov, oi);
    }
    if ((t & 63) == 0) {
        int w = t >> 6;
        wse[w] = se;
#pragma unroll
        for (int q = 0; q < KNN; ++q) { wv[w][q] = v[q]; wi[w][q] = id[q]; }
    }
    __syncthreads();
    if (t == 0) {
        float av[KNN]; int ai[KNN];
#pragma unroll
        for (int q = 0; q < KNN; ++q) { av[q] = wv[0][q]; ai[q] = wi[0][q]; }
        for (int w = 1; w < 5; ++w) {
            float bv[KNN]; int bi[KNN];
#pragma unroll
            for (int q = 0; q < KNN; ++q) { bv[q] = wv[w][q]; bi[q] = wi[w][q]; }
            merge5(av, ai, bv, bi);
        }
        float tot = wse[0] + wse[1] + wse[2] + wse[3] + wse[4];
        s_lse = logf(tot) + INV_TAU;
#pragma unroll
        for (int q = 0; q < KNN; ++q) c5[q] = ai[q];
    }
    __syncthreads();

    // ---- phase 2: exact rescan of 5 candidate chunks (320 = 5x64 threads)
    const int q = c5[t >> 6] * 64 + (t & 63);
    float dv = 0.0f;
    for (int d = 0; d < DIM; d += 8) {
        bf16x8 qv = *(const bf16x8*)(Qt + tidx(q, d));
#pragma unroll
        for (int e = 0; e < 8; ++e)
            dv = fmaf(bf2f((unsigned short)qv[e]), tn_sh[d + e], dv);
    }
    for (int k = 0; k < KNN; ++k) {
        float vv = dv; int qq = q;
#pragma unroll
        for (int d2 = 1; d2 <= 32; d2 <<= 1) {
            float ov = __shfl_xor(vv, d2); int oq = __shfl_xor(qq, d2);
            bool bet = (ov > vv) || (ov == vv && oq < qq);
            vv = bet ? ov : vv; qq = bet ? oq : qq;
        }
        if ((t & 63) == 0) { rv[t >> 6] = vv; rq[t >> 6] = qq; }
        __syncthreads();
        if (t == 0) {
            float bv = rv[0]; int bq = rq[0];
            for (int w = 1; w < 5; ++w) {
                bool bet = (rv[w] > bv) || (rv[w] == bv && rq[w] < bq);
                if (bet) { bv = rv[w]; bq = rq[w]; }
            }
            winq = bq; t5s[k] = bq;
        }
        __syncthreads();
        if (q == winq) dv = NEG_INF;
        __syncthreads();
    }
    if (t == 0) {
        int lab[KNN];
#pragma unroll
        for (int k = 0; k < KNN; ++k) {
            int j = t5s[k];
            lab[k] = (j < BSZ) ? slab[j] : qlab[j];
        }
        int bestc = 0, bestl = 0x7fffffff;
#pragma unroll
        for (int k = 0; k < KNN; ++k) {
            int c2 = 0;
#pragma unroll
            for (int w = 0; w < KNN; ++w) c2 += (lab[w] == lab[k]) ? 1 : 0;
            if (c2 > bestc || (c2 == bestc && lab[k] < bestl)) { bestc = c2; bestl = lab[k]; }
        }
        s_ps = bestl;
    }
    __syncthreads();

    // ---- phase 3: rowloss = -(Tn[row].CS[ps] * invtau - pc*lse) / max(pc,1)
    const int ps = s_ps;
    float dd = (t < DIM) ? tn_sh[t] * CS[ps * DIM + t] : 0.0f;
#pragma unroll
    for (int o2 = 32; o2; o2 >>= 1) dd += __shfl_xor(dd, o2);
    if ((t & 63) == 0) dred[t >> 6] = dd;
    __syncthreads();
    if (t == 0) {
        float d = dred[0] + dred[1] + dred[2] + dred[3] + dred[4];
        float pc = (float)cnt[ps];
        rowloss[row] = -(d * INV_TAU - pc * s_lse) / fmaxf(pc, 1.0f);
    }
}

// ---------- K5: final reduction -------------------------------------------------------
__global__ __launch_bounds__(256) void k_final(const float* __restrict__ rowloss,
                                               const int* __restrict__ itp,
                                               float* __restrict__ out) {
    __shared__ float red[256];
    int t = threadIdx.x;
    red[t] = rowloss[t] + rowloss[t + 256];
    __syncthreads();
    for (int k = 128; k; k >>= 1) {
        if (t < k) red[t] += red[t + k];
        __syncthreads();
    }
    if (t == 0) out[0] = ((itp[0] > WARM) ? COEFF_V : 0.0f) * (red[0] / (float)BSZ);
}

// ---------- launcher ------------------------------------------------------------------
extern "C" void kernel_launch(void* const* d_in, const int* in_sizes, int n_in,
                              void* d_out, int out_size, void* d_ws, size_t ws_size,
                              hipStream_t stream) {
    const float* feat  = (const float*)d_in[0];
    const int*   slab  = (const int*)d_in[1];
    const int*   itp   = (const int*)d_in[2];
    const float* queue = (const float*)d_in[3];
    const int*   qlab  = (const int*)d_in[4];
    float* out = (float*)d_out;

    char* ws = (char*)d_ws;
    unsigned short* Qt = (unsigned short*)(ws);            // 24,576,000
    unsigned short* Tt = (unsigned short*)(ws + 24576000); //    262,144
    float* CS      = (float*)(ws + 24838144);              //    129,024
    int*   cnt     = (int*)  (ws + 24967168);              //        512
    int*   off     = (int*)  (ws + 24967680);              //        512
    int*   list    = (int*)  (ws + 24968192);              //    192,000
    float* pse     = (float*)(ws + 25160192);              //  1,536,000
    float* pmax    = (float*)(ws + 26696192);              //  1,536,000
    float* rowloss = (float*)(ws + 28232192);              //      2,048

    hipLaunchKernelGGL(k_prep, dim3((BSZ + NQ + 3) / 4), dim3(256), 0, stream, feat, queue, Tt, Qt);
    hipLaunchKernelGGL(k_sort, dim3(1), dim3(1024), 0, stream, slab, qlab, cnt, off, list, CS);
    hipLaunchKernelGGL(k_cs2, dim3(NCLS, 8), dim3(256), 0, stream, Qt, off, list, CS);
    hipLaunchKernelGGL(k_gemm2, dim3(1500), dim3(256), 0, stream, Tt, Qt, pse, pmax);
    hipLaunchKernelGGL(k_tail, dim3(BSZ), dim3(320), 0, stream, Tt, Qt, pse, pmax, CS, cnt, slab, qlab, rowloss);
    hipLaunchKernelGGL(k_final, dim3(1), dim3(256), 0, stream, rowloss, itp, out);
}